// Round 1
// baseline (1303.192 us; speedup 1.0000x reference)
//
#include <hip/hip_runtime.h>

#define NROWS 524288
#define NCH 128

// ws float layout:
// [0,      16384) : gram accumulator
// [16384,  16512) : column sums
// [16512,  32896) : W = inv_sqrt (row-major [j][i], zeros above diagonal)
// [32896,  33024) : bias[j] = sum_i m_i * W[j][i]

__global__ __launch_bounds__(256) void k_gram(const float* __restrict__ x,
                                              float* __restrict__ gram,
                                              float* __restrict__ colsum) {
    __shared__ float xs[64][132];   // 64-row chunk, padded stride
    const int tid = threadIdx.x;
    const int ty = tid >> 4;        // 0..15 -> Gram rows ty*8..+7
    const int tx = tid & 15;        // 0..15 -> Gram cols tx*8..+7
    float acc[8][8];
#pragma unroll
    for (int a = 0; a < 8; ++a)
#pragma unroll
        for (int b = 0; b < 8; ++b) acc[a][b] = 0.f;
    float csum = 0.f;

    for (int chunk = blockIdx.x; chunk < NROWS / 64; chunk += gridDim.x) {
        const float4* src = (const float4*)(x + (size_t)chunk * 64 * NCH);
        __syncthreads();            // protect xs from previous iteration readers
#pragma unroll
        for (int f = tid; f < 64 * 32; f += 256) {
            int r = f >> 5, c4 = f & 31;
            *(float4*)&xs[r][c4 << 2] = src[f];
        }
        __syncthreads();
#pragma unroll 2
        for (int r = 0; r < 64; ++r) {
            float4 a0 = *(const float4*)&xs[r][ty * 8];
            float4 a1 = *(const float4*)&xs[r][ty * 8 + 4];
            float4 b0 = *(const float4*)&xs[r][tx * 8];
            float4 b1 = *(const float4*)&xs[r][tx * 8 + 4];
            float av[8] = {a0.x, a0.y, a0.z, a0.w, a1.x, a1.y, a1.z, a1.w};
            float bv[8] = {b0.x, b0.y, b0.z, b0.w, b1.x, b1.y, b1.z, b1.w};
#pragma unroll
            for (int a = 0; a < 8; ++a)
#pragma unroll
                for (int b = 0; b < 8; ++b) acc[a][b] += av[a] * bv[b];
        }
        if (tid < NCH) {
            float s = 0.f;
#pragma unroll 8
            for (int r = 0; r < 64; ++r) s += xs[r][tid];
            csum += s;
        }
    }
#pragma unroll
    for (int a = 0; a < 8; ++a)
#pragma unroll
        for (int b = 0; b < 8; ++b)
            atomicAdd(&gram[(ty * 8 + a) * NCH + tx * 8 + b], acc[a][b]);
    if (tid < NCH) atomicAdd(&colsum[tid], csum);
}

__global__ __launch_bounds__(256) void k_chol(const float* __restrict__ gram,
                                              const float* __restrict__ colsum,
                                              float* __restrict__ Wout,
                                              float* __restrict__ bias) {
    __shared__ float A[128][129];
    __shared__ float X[128][129];
    __shared__ float m[128];
    __shared__ float dinv[128];
    const int tid = threadIdx.x;

    if (tid < 128) m[tid] = colsum[tid] * (1.0f / (float)NROWS);
    __syncthreads();
    for (int idx = tid; idx < 128 * 128; idx += 256) {
        int i = idx >> 7, j = idx & 127;
        A[i][j] = (gram[idx] - (float)NROWS * m[i] * m[j]) * (1.0f / (float)(NROWS - 1));
    }
    for (int idx = tid; idx < 128 * 129; idx += 256) ((float*)X)[idx] = 0.f;
    __syncthreads();

    // Cholesky (lower), right-looking
    for (int k = 0; k < 128; ++k) {
        if (tid == 0) {
            float d = sqrtf(A[k][k]);
            A[k][k] = d;
            dinv[k] = 1.0f / d;
        }
        __syncthreads();
        for (int j = k + 1 + tid; j < 128; j += 256) A[j][k] *= dinv[k];
        __syncthreads();
        for (int j = k + 1 + tid; j < 128; j += 256) {
            float ljk = A[j][k];
            for (int i = k + 1; i <= j; ++i) A[j][i] -= ljk * A[i][k];
        }
        __syncthreads();
    }

    // X = L^{-1} (lower). Lane c owns column c; uniform loops, zeros elsewhere.
    if (tid < 128) X[tid][tid] = dinv[tid];
    __syncthreads();
    if (tid < 128) {
        const int c = tid;
        for (int r = 1; r < 128; ++r) {
            float s = 0.f;
            for (int k2 = 0; k2 < r; ++k2) s += A[r][k2] * X[k2][c];
            if (c < r) X[r][c] = -s * dinv[r];
        }
    }
    __syncthreads();

    if (tid < 128) {
        const int j = tid;
        float b = 0.f;
        for (int i = 0; i <= j; ++i) b += m[i] * X[j][i];
        bias[j] = b;
    }
    for (int idx = tid; idx < 128 * 128; idx += 256)
        Wout[idx] = X[idx >> 7][idx & 127];
}

__global__ __launch_bounds__(512) void k_apply(const float* __restrict__ x,
                                               const float* __restrict__ Wg,
                                               const float* __restrict__ bias,
                                               float* __restrict__ out) {
    __shared__ float xs[128 * 128];  // swizzled: quad q_phys = q ^ ((r>>2)&7)
    __shared__ float Ws[128 * 128];  // swizzled: quad q_phys = q ^ ((r>>3)&7)
    __shared__ float bsh[128];
    const int tid = threadIdx.x;

    for (int f = tid; f < 4096; f += 512) {
        int r = f >> 5, c4 = f & 31;
        ((float4*)&Ws[r * 128])[c4 ^ ((r >> 3) & 7)] = ((const float4*)Wg)[f];
    }
    if (tid < 128) bsh[tid] = bias[tid];
    const float4* src = (const float4*)(x + (size_t)blockIdx.x * 128 * NCH);
    for (int f = tid; f < 4096; f += 512) {
        int r = f >> 5, c4 = f & 31;
        ((float4*)&xs[r * 128])[c4 ^ ((r >> 2) & 7)] = src[f];
    }
    __syncthreads();

    const int ry = tid >> 4;  // 0..31 -> rows ry*4..+3
    const int cx = tid & 15;  // 0..15 -> cols cx*4..+3 and 64+cx*4..+3
    float acc[4][8];
#pragma unroll
    for (int a = 0; a < 4; ++a)
#pragma unroll
        for (int b = 0; b < 8; ++b) acc[a][b] = 0.f;

#pragma unroll 2
    for (int i4 = 0; i4 < 32; ++i4) {
        float4 xv[4], wv[8];
#pragma unroll
        for (int a = 0; a < 4; ++a) {
            int r = ry * 4 + a;
            xv[a] = ((const float4*)&xs[r * 128])[i4 ^ ((r >> 2) & 7)];
        }
#pragma unroll
        for (int b = 0; b < 8; ++b) {
            int r = (b < 4) ? (cx * 4 + b) : (64 + cx * 4 + (b - 4));
            wv[b] = ((const float4*)&Ws[r * 128])[i4 ^ ((r >> 3) & 7)];
        }
#pragma unroll
        for (int a = 0; a < 4; ++a)
#pragma unroll
            for (int b = 0; b < 8; ++b)
                acc[a][b] += xv[a].x * wv[b].x + xv[a].y * wv[b].y +
                             xv[a].z * wv[b].z + xv[a].w * wv[b].w;
    }

    float* dst = out + (size_t)blockIdx.x * 128 * NCH;
#pragma unroll
    for (int a = 0; a < 4; ++a) {
        int row = ry * 4 + a;
        float4 o0, o1;
        o0.x = acc[a][0] - bsh[cx * 4 + 0];
        o0.y = acc[a][1] - bsh[cx * 4 + 1];
        o0.z = acc[a][2] - bsh[cx * 4 + 2];
        o0.w = acc[a][3] - bsh[cx * 4 + 3];
        o1.x = acc[a][4] - bsh[64 + cx * 4 + 0];
        o1.y = acc[a][5] - bsh[64 + cx * 4 + 1];
        o1.z = acc[a][6] - bsh[64 + cx * 4 + 2];
        o1.w = acc[a][7] - bsh[64 + cx * 4 + 3];
        *(float4*)&dst[row * 128 + cx * 4] = o0;
        *(float4*)&dst[row * 128 + 64 + cx * 4] = o1;
    }
}

extern "C" void kernel_launch(void* const* d_in, const int* in_sizes, int n_in,
                              void* d_out, int out_size, void* d_ws, size_t ws_size,
                              hipStream_t stream) {
    const float* x = (const float*)d_in[0];
    float* ws = (float*)d_ws;
    float* gram = ws;                 // 16384
    float* colsum = ws + 16384;       // 128
    float* W = ws + 16512;            // 16384
    float* bias = ws + 32896;         // 128
    float* out = (float*)d_out;

    hipMemsetAsync(d_ws, 0, (16384 + 128) * sizeof(float), stream);
    k_gram<<<512, 256, 0, stream>>>(x, gram, colsum);
    k_chol<<<1, 256, 0, stream>>>(gram, colsum, W, bias);
    k_apply<<<NROWS / 128, 512, 0, stream>>>(x, W, bias, out);
}

// Round 2
// 946.008 us; speedup vs baseline: 1.3776x; 1.3776x over previous
//
#include <hip/hip_runtime.h>

#define NROWS 524288
#define NCH 128

// ws float layout:
// [0,      16384) : gram accumulator
// [16384,  16512) : column sums
// [16512,  32896) : W = inv_sqrt (row-major [j][i], zeros above diagonal)
// [32896,  33024) : bias[j] = sum_i m_i * W[j][i]

__global__ __launch_bounds__(256) void k_gram(const float* __restrict__ x,
                                              float* __restrict__ gram,
                                              float* __restrict__ colsum) {
    __shared__ float xs[64][132];   // 64-row chunk, padded stride
    const int tid = threadIdx.x;
    const int ty = tid >> 4;        // 0..15 -> Gram rows ty*8..+7
    const int tx = tid & 15;        // 0..15 -> Gram cols tx*8..+7
    float acc[8][8];
#pragma unroll
    for (int a = 0; a < 8; ++a)
#pragma unroll
        for (int b = 0; b < 8; ++b) acc[a][b] = 0.f;
    float csum = 0.f;

    for (int chunk = blockIdx.x; chunk < NROWS / 64; chunk += gridDim.x) {
        const float4* src = (const float4*)(x + (size_t)chunk * 64 * NCH);
        __syncthreads();            // protect xs from previous iteration readers
#pragma unroll
        for (int f = tid; f < 64 * 32; f += 256) {
            int r = f >> 5, c4 = f & 31;
            *(float4*)&xs[r][c4 << 2] = src[f];
        }
        __syncthreads();
#pragma unroll 2
        for (int r = 0; r < 64; ++r) {
            float4 a0 = *(const float4*)&xs[r][ty * 8];
            float4 a1 = *(const float4*)&xs[r][ty * 8 + 4];
            float4 b0 = *(const float4*)&xs[r][tx * 8];
            float4 b1 = *(const float4*)&xs[r][tx * 8 + 4];
            float av[8] = {a0.x, a0.y, a0.z, a0.w, a1.x, a1.y, a1.z, a1.w};
            float bv[8] = {b0.x, b0.y, b0.z, b0.w, b1.x, b1.y, b1.z, b1.w};
#pragma unroll
            for (int a = 0; a < 8; ++a)
#pragma unroll
                for (int b = 0; b < 8; ++b) acc[a][b] += av[a] * bv[b];
        }
        if (tid < NCH) {
            float s = 0.f;
#pragma unroll 8
            for (int r = 0; r < 64; ++r) s += xs[r][tid];
            csum += s;
        }
    }
#pragma unroll
    for (int a = 0; a < 8; ++a)
#pragma unroll
        for (int b = 0; b < 8; ++b)
            atomicAdd(&gram[(ty * 8 + a) * NCH + tx * 8 + b], acc[a][b]);
    if (tid < NCH) atomicAdd(&colsum[tid], csum);
}

// Parallel Cholesky + triangular inverse, single block, 256 threads.
// Phase 1: outer-product elimination on symmetric A (full trailing square,
//          1 barrier per k, pivots D_k left on the diagonal, column k of the
//          unscaled L left below the diagonal).
// Phase 2: forward-substitution elimination of B = I vectorized over RHS
//          columns (1 barrier per r).  X = L^{-1} recovered by lazy scaling:
//          X[j][c] = B[j][c] / sqrt(D_j).
__global__ __launch_bounds__(256) void k_chol(const float* __restrict__ gram,
                                              const float* __restrict__ colsum,
                                              float* __restrict__ Wout,
                                              float* __restrict__ bias) {
    __shared__ float A[128][129];
    __shared__ float B[128][129];
    __shared__ float m[128];
    __shared__ float dsq[128];   // 1/sqrt(D_k)
    __shared__ float rd2[128];   // 1/D_k
    const int tid = threadIdx.x;

    if (tid < 128) m[tid] = colsum[tid] * (1.0f / (float)NROWS);
    __syncthreads();
    for (int idx = tid; idx < 128 * 128; idx += 256) {
        int i = idx >> 7, j = idx & 127;
        A[i][j] = (gram[idx] - (float)NROWS * m[i] * m[j]) * (1.0f / (float)(NROWS - 1));
        B[i][j] = (i == j) ? 1.0f : 0.0f;
    }

    // Phase 1: Cholesky elimination (symmetric square trailing update).
    const int q = tid >> 1;      // row selector
    const int h = tid & 1;       // column parity
    for (int k = 0; k < 127; ++k) {
        __syncthreads();
        float rd = 1.0f / A[k][k];             // LDS broadcast, redundant per thread
        int j = k + 1 + q;
        if (j < 128) {
            float fj = A[j][k] * rd;
            for (int i = k + 1 + h; i < 128; i += 2)
                A[j][i] -= fj * A[k][i];
        }
    }
    __syncthreads();
    if (tid < 128) {
        float d = A[tid][tid];
        dsq[tid] = 1.0f / sqrtf(d);
        rd2[tid] = 1.0f / d;
    }

    // Phase 2: forward substitution, all 128 RHS columns at once.
    for (int r = 0; r < 127; ++r) {
        __syncthreads();
        int j = r + 1 + q;
        if (j < 128) {
            float f = A[j][r] * rd2[r];        // = L[j][r]/L[r][r]
            for (int c = h; c <= r; c += 2)
                B[j][c] -= f * B[r][c];
        }
    }
    __syncthreads();

    // Outputs. X[j][c] = B[j][c]*dsq[j] (c<j), X[j][j] = dsq[j], 0 above.
    if (tid < 128) {
        const int j = tid;
        float s = 0.f;
        for (int i = 0; i <= j; ++i) s += m[i] * B[j][i];
        bias[j] = s * dsq[j];
    }
    for (int idx = tid; idx < 128 * 128; idx += 256) {
        int j = idx >> 7, c = idx & 127;
        float v = (c < j) ? B[j][c] * dsq[j] : ((c == j) ? dsq[j] : 0.0f);
        Wout[idx] = v;
    }
}

__global__ __launch_bounds__(512) void k_apply(const float* __restrict__ x,
                                               const float* __restrict__ Wg,
                                               const float* __restrict__ bias,
                                               float* __restrict__ out) {
    __shared__ float xs[128 * 128];  // swizzled: quad q_phys = q ^ ((r>>2)&7)
    __shared__ float Ws[128 * 128];  // swizzled: quad q_phys = q ^ ((r>>3)&7)
    __shared__ float bsh[128];
    const int tid = threadIdx.x;

    for (int f = tid; f < 4096; f += 512) {
        int r = f >> 5, c4 = f & 31;
        ((float4*)&Ws[r * 128])[c4 ^ ((r >> 3) & 7)] = ((const float4*)Wg)[f];
    }
    if (tid < 128) bsh[tid] = bias[tid];
    const float4* src = (const float4*)(x + (size_t)blockIdx.x * 128 * NCH);
    for (int f = tid; f < 4096; f += 512) {
        int r = f >> 5, c4 = f & 31;
        ((float4*)&xs[r * 128])[c4 ^ ((r >> 2) & 7)] = src[f];
    }
    __syncthreads();

    const int ry = tid >> 4;  // 0..31 -> rows ry*4..+3
    const int cx = tid & 15;  // 0..15 -> cols cx*4..+3 and 64+cx*4..+3
    float acc[4][8];
#pragma unroll
    for (int a = 0; a < 4; ++a)
#pragma unroll
        for (int b = 0; b < 8; ++b) acc[a][b] = 0.f;

#pragma unroll 2
    for (int i4 = 0; i4 < 32; ++i4) {
        float4 xv[4], wv[8];
#pragma unroll
        for (int a = 0; a < 4; ++a) {
            int r = ry * 4 + a;
            xv[a] = ((const float4*)&xs[r * 128])[i4 ^ ((r >> 2) & 7)];
        }
#pragma unroll
        for (int b = 0; b < 8; ++b) {
            int r = (b < 4) ? (cx * 4 + b) : (64 + cx * 4 + (b - 4));
            wv[b] = ((const float4*)&Ws[r * 128])[i4 ^ ((r >> 3) & 7)];
        }
#pragma unroll
        for (int a = 0; a < 4; ++a)
#pragma unroll
            for (int b = 0; b < 8; ++b)
                acc[a][b] += xv[a].x * wv[b].x + xv[a].y * wv[b].y +
                             xv[a].z * wv[b].z + xv[a].w * wv[b].w;
    }

    float* dst = out + (size_t)blockIdx.x * 128 * NCH;
#pragma unroll
    for (int a = 0; a < 4; ++a) {
        int row = ry * 4 + a;
        float4 o0, o1;
        o0.x = acc[a][0] - bsh[cx * 4 + 0];
        o0.y = acc[a][1] - bsh[cx * 4 + 1];
        o0.z = acc[a][2] - bsh[cx * 4 + 2];
        o0.w = acc[a][3] - bsh[cx * 4 + 3];
        o1.x = acc[a][4] - bsh[64 + cx * 4 + 0];
        o1.y = acc[a][5] - bsh[64 + cx * 4 + 1];
        o1.z = acc[a][6] - bsh[64 + cx * 4 + 2];
        o1.w = acc[a][7] - bsh[64 + cx * 4 + 3];
        *(float4*)&dst[row * 128 + cx * 4] = o0;
        *(float4*)&dst[row * 128 + 64 + cx * 4] = o1;
    }
}

extern "C" void kernel_launch(void* const* d_in, const int* in_sizes, int n_in,
                              void* d_out, int out_size, void* d_ws, size_t ws_size,
                              hipStream_t stream) {
    const float* x = (const float*)d_in[0];
    float* ws = (float*)d_ws;
    float* gram = ws;                 // 16384
    float* colsum = ws + 16384;       // 128
    float* W = ws + 16512;            // 16384
    float* bias = ws + 32896;         // 128
    float* out = (float*)d_out;

    hipMemsetAsync(d_ws, 0, (16384 + 128) * sizeof(float), stream);
    k_gram<<<512, 256, 0, stream>>>(x, gram, colsum);
    k_chol<<<1, 256, 0, stream>>>(gram, colsum, W, bias);
    k_apply<<<NROWS / 128, 512, 0, stream>>>(x, W, bias, out);
}